// Round 4
// baseline (224.538 us; speedup 1.0000x reference)
//
#include <hip/hip_runtime.h>
#include <hip/hip_bf16.h>

// ---------------------------------------------------------------------------
// SlidingWindowAttention: fused QKV projection (bf16 MFMA GEMM) + windowed
// flash attention (bf16 MFMA, S^T trick).
// GEMM (m201-style): 256x256 tile, BK=64, 512 thr, 8 waves 2Mx4N with
// per-wave 128x64 output (acc[8][4]). Double-buffered LDS (128 KiB), 4 fine
// phases per K-tile: {ds_read frag subtile ∥ stage slice → bar → 16 MFMA
// (setprio) → bar}. B-frags read once per tile, held in regs (0.375
// reads/MFMA vs 0.5 before => LDS-bound MfmaUtil ceiling 68% vs 49%).
// Ordering rule (round-2 lesson): vmcnt covering tile t+1 sits BEFORE the
// barrier that precedes t+1's reads (end of phase 3).
// Q,K stored head-major [b][h][s][d]; V stored transposed [b][h][d][s].
// B=4, S=2048, D=1024, H=16, hd=64, WINDOW=128.
// ---------------------------------------------------------------------------

#define NB 4
#define SQ 2048
#define NH 16
#define HD 64
#define DM 1024
#define WIN 128

typedef unsigned short u16;
typedef __bf16 bf16x8 __attribute__((ext_vector_type(8)));
typedef unsigned short us8 __attribute__((ext_vector_type(8)));
typedef unsigned short us4v __attribute__((ext_vector_type(4)));
typedef float f32x4 __attribute__((ext_vector_type(4)));

__device__ __forceinline__ u16 f2b(float f) {
  union { float f; unsigned u; } v; v.f = f;
  unsigned r = v.u + 0x7FFFu + ((v.u >> 16) & 1u);   // RNE
  return (u16)(r >> 16);
}

__device__ __forceinline__ bf16x8 as_bf(us8 v) {
  union { us8 a; bf16x8 b; } u; u.a = v; return u.b;
}

__device__ __forceinline__ f32x4 mfma16(bf16x8 a, bf16x8 b, f32x4 c) {
  return __builtin_amdgcn_mfma_f32_16x16x32_bf16(a, b, c, 0, 0, 0);
}

// async global->LDS, 16B per lane; LDS dest is wave-uniform base + lane*16
__device__ __forceinline__ void gl_lds16(const u16* g, u16* l) {
#if __has_builtin(__builtin_amdgcn_global_load_lds)
  __builtin_amdgcn_global_load_lds(
      (const __attribute__((address_space(1))) void*)g,
      (__attribute__((address_space(3))) void*)l, 16, 0, 0);
#else
  int lane = threadIdx.x & 63;
  *(us8*)(l + lane * 8) = *(const us8*)g;
#endif
}

// raw barrier with scheduler fences on both sides: no vmcnt(0) drain, and
// neither LDS reads (above) nor MFMAs (below) may cross it (rule 18).
#define MIDBAR()                                   \
  do {                                             \
    __builtin_amdgcn_sched_barrier(0);             \
    asm volatile("s_barrier" ::: "memory");        \
    __builtin_amdgcn_sched_barrier(0);             \
  } while (0)

// ---------------------------------------------------------------------------
// 1) prep: X fp32->bf16 (blocks 0..8191) ; W^T bf16 (blocks 8192..11263)
// ---------------------------------------------------------------------------
__global__ void k_prep(const float* __restrict__ X, u16* __restrict__ Xb,
                       const float* __restrict__ W0,
                       const float* __restrict__ W1,
                       const float* __restrict__ W2, u16* __restrict__ Wt) {
  int bx = blockIdx.x;
  int t = threadIdx.x;
  if (bx < 8192) {
    int idx = bx * 256 + t;
    float4 v = ((const float4*)X)[idx];
    us4v o = { f2b(v.x), f2b(v.y), f2b(v.z), f2b(v.w) };
    ((us4v*)Xb)[idx] = o;
    return;
  }
  int tb = bx - 8192;
  int mat = tb >> 10, rem = tb & 1023;
  const float* W = mat == 0 ? W0 : (mat == 1 ? W1 : W2);
  u16* dst = Wt + (size_t)mat * DM * DM;
  __shared__ float tile[32][33];
  int n0 = (rem & 31) * 32, k0 = (rem >> 5) * 32;
  int c = t & 31, r8 = t >> 5;
  for (int p = 0; p < 4; ++p) {
    int r = p * 8 + r8;
    tile[r][c] = W[(size_t)(k0 + r) * DM + n0 + c];
  }
  __syncthreads();
  for (int p = 0; p < 4; ++p) {
    int r = p * 8 + r8;
    dst[(size_t)(n0 + r) * DM + k0 + c] = f2b(tile[c][r]);
  }
}

// ---------------------------------------------------------------------------
// 2) GEMM: 256x256 tile, BK=64, 512 threads, waves 2Mx4N, 128x64 per wave.
//    Double-buffered LDS, 4 phases/K-tile, vmcnt(0) at end of phase 3 only
//    (t+1's 8 loads issued in phases 0-1 => >=2 phases of latency cover).
//    XOR-swizzled packed LDS (slot kg ^ (row&7)) -> conflict-free ds_read_b128.
//    Epilogues: mat 0/1 (Q,K) -> head-major [b][h][s][d];
//               mat 2  (V)   -> transposed [b][h][d][s] (8B vector stores).
// ---------------------------------------------------------------------------
__global__ __launch_bounds__(512, 2) void k_gemm(
    const u16* __restrict__ Xb, const u16* __restrict__ Wt,
    const float* __restrict__ bq, const float* __restrict__ bk,
    const float* __restrict__ bv,
    u16* __restrict__ Qh, u16* __restrict__ Kh, u16* __restrict__ VtG) {
  int mat = blockIdx.y >> 2;
  int n0 = (blockIdx.y & 3) * 256;
  int m0 = blockIdx.x * 256;
  const u16* Bw = Wt + (size_t)mat * DM * DM;
  const float* bias = mat == 0 ? bq : (mat == 1 ? bk : bv);

  // double buffer: A 256x64 + B 256x64 bf16 each = 128 KiB total
  __shared__ u16 As[2][256 * 64];
  __shared__ u16 Bs[2][256 * 64];

  int tid = threadIdx.x;
  int lane = tid & 63, wave = tid >> 6;      // wave 0..7
  int wm = wave >> 2, wn = wave & 3;         // 2M x 4N, per-wave 128x64
  int col = lane & 15, g = lane >> 4;

  // staging: row = wave*32 + i*8 + (lane>>3), slot = (lane&7) ^ (row&7)
  int srow = lane >> 3;
  int skg = (lane & 7) ^ srow;
  const u16* gA = Xb + (size_t)(m0 + wave * 32 + srow) * DM + skg * 8;
  const u16* gB = Bw + (size_t)(n0 + wave * 32 + srow) * DM + skg * 8;

  f32x4 zero4 = {0.f, 0.f, 0.f, 0.f};
  f32x4 acc[8][4];
  for (int i = 0; i < 8; ++i)
    for (int j = 0; j < 4; ++j) acc[i][j] = zero4;

#define STAGE_A4(kt, bi)                                                \
  do {                                                                  \
    _Pragma("unroll") for (int i = 0; i < 4; ++i)                       \
      gl_lds16(gA + (size_t)i * 8 * DM + (kt) * 64,                     \
               &As[bi][(wave * 32 + i * 8) * 64]);                      \
  } while (0)
#define STAGE_B4(kt, bi)                                                \
  do {                                                                  \
    _Pragma("unroll") for (int j = 0; j < 4; ++j)                       \
      gl_lds16(gB + (size_t)j * 8 * DM + (kt) * 64,                     \
               &Bs[bi][(wave * 32 + j * 8) * 64]);                      \
  } while (0)

// read the two A-frags (mi = 2p, 2p+1) for both ks halves from buffer cur
#define PH_READ_A(p)                                                    \
  _Pragma("unroll") for (int ks = 0; ks < 2; ++ks) {                    \
    int kg = ((ks * 4 + g) ^ (col & 7)) * 8;                            \
    af[ks][0] = *(const bf16x8*)&As[cur][(wm * 128 + (p) * 32 + col) *  \
                                         64 + kg];                      \
    af[ks][1] = *(const bf16x8*)&As[cur][(wm * 128 + (p) * 32 + 16 +    \
                                          col) * 64 + kg];              \
  }

#define PH_MFMA(p)                                                      \
  do {                                                                  \
    __builtin_amdgcn_s_setprio(1);                                      \
    _Pragma("unroll") for (int ks = 0; ks < 2; ++ks)                    \
      _Pragma("unroll") for (int m2 = 0; m2 < 2; ++m2)                  \
        _Pragma("unroll") for (int ni = 0; ni < 4; ++ni)                \
          acc[(p) * 2 + m2][ni] =                                       \
              mfma16(af[ks][m2], bfr[ks][ni], acc[(p) * 2 + m2][ni]);   \
    __builtin_amdgcn_s_setprio(0);                                      \
  } while (0)

  // prologue: tile 0 -> buf 0; publish before any read
  STAGE_A4(0, 0);
  STAGE_B4(0, 0);
  asm volatile("s_waitcnt vmcnt(0)" ::: "memory");
  MIDBAR();

  for (int t = 0; t < 16; ++t) {
    int cur = t & 1, nxt = cur ^ 1;
    bf16x8 bfr[2][4], af[2][2];
    // ---- phase 0: read all B-frags + A(0,1); stage A of t+1 ----
#pragma unroll
    for (int ks = 0; ks < 2; ++ks) {
      int kg = ((ks * 4 + g) ^ (col & 7)) * 8;
#pragma unroll
      for (int ni = 0; ni < 4; ++ni)
        bfr[ks][ni] =
            *(const bf16x8*)&Bs[cur][(wn * 64 + ni * 16 + col) * 64 + kg];
    }
    PH_READ_A(0);
    if (t < 15) STAGE_A4(t + 1, nxt);
    MIDBAR();
    PH_MFMA(0);
    MIDBAR();
    // ---- phase 1: read A(2,3); stage B of t+1 ----
    PH_READ_A(1);
    if (t < 15) STAGE_B4(t + 1, nxt);
    MIDBAR();
    PH_MFMA(1);
    MIDBAR();
    // ---- phase 2: read A(4,5) ----
    PH_READ_A(2);
    MIDBAR();
    PH_MFMA(2);
    MIDBAR();
    // ---- phase 3: read A(6,7); vmcnt covers tile t+1 before barrier ----
    PH_READ_A(3);
    if (t < 15) asm volatile("s_waitcnt vmcnt(0)" ::: "memory");
    MIDBAR();
    PH_MFMA(3);
    MIDBAR();
  }

#undef PH_MFMA
#undef PH_READ_A
#undef STAGE_A4
#undef STAGE_B4

  float bvv[4];
  for (int ni = 0; ni < 4; ++ni)
    bvv[ni] = bias[n0 + wn * 64 + ni * 16 + col];

  if (mat < 2) {
    // head-major: addr = ((b*NH + h)*SQ + s)*HD + d
    u16* C = mat == 0 ? Qh : Kh;
    for (int mi = 0; mi < 8; ++mi) {
      int m = m0 + wm * 128 + mi * 16 + g * 4;
      int bb = m >> 11, s0 = m & 2047;
      for (int r = 0; r < 4; ++r) {
        size_t base = ((size_t)(bb * NH) * SQ + (s0 + r)) * HD;
        for (int ni = 0; ni < 4; ++ni) {
          int n = n0 + wn * 64 + ni * 16 + col;
          int h = n >> 6, d = n & 63;
          C[base + (size_t)h * SQ * HD + d] = f2b(acc[mi][ni][r] + bvv[ni]);
        }
      }
    }
  } else {
    // V^T: [b][h][d][s]; rows of C are consecutive tokens s -> 8B stores
    for (int mi = 0; mi < 8; ++mi) {
      int m = m0 + wm * 128 + mi * 16 + g * 4;
      int bb = m >> 11, s0 = m & 2047;
      for (int ni = 0; ni < 4; ++ni) {
        int n = n0 + wn * 64 + ni * 16 + col;
        us4v ov = { f2b(acc[mi][ni][0] + bvv[ni]), f2b(acc[mi][ni][1] + bvv[ni]),
                    f2b(acc[mi][ni][2] + bvv[ni]), f2b(acc[mi][ni][3] + bvv[ni]) };
        *(us4v*)&VtG[((size_t)(bb * 1024 + n)) * SQ + s0] = ov;
      }
    }
  }
}

// ---------------------------------------------------------------------------
// 3) Windowed flash attention. Block = 4 waves; each wave owns 32 queries of
//    one (b,h), loops over 5 key-chunks of 64. S^T = K*Q^T so each lane holds
//    4 consecutive keys -> vectorized P stores. All global loads line-exact
//    (Q,K head-major; V^T key-contiguous). No __syncthreads.
// ---------------------------------------------------------------------------
__global__ __launch_bounds__(256) void k_attn(
    const u16* __restrict__ Qh, const u16* __restrict__ Kh,
    const u16* __restrict__ VtG, float* __restrict__ out) {
  int bid = blockIdx.x;
  int b = bid >> 8;
  int h = (bid >> 4) & 15;
  int q0 = (bid & 15) << 7;
  int tid = threadIdx.x, lane = tid & 63, wave = tid >> 6;
  int col = lane & 15, g = lane >> 4;
  int qw = q0 + wave * 32;

  __shared__ u16 Ps[4][32 * 72];
  u16* Pw = Ps[wave];

  const u16* Qp = Qh + (size_t)(b * NH + h) * SQ * HD;
  const u16* Kp = Kh + (size_t)(b * NH + h) * SQ * HD;
  const u16* Vt = VtG + (size_t)(b * 1024 + h * 64) * SQ;

  // Q fragments (B operand: lane col = query, contiguous d)
  bf16x8 qf[2][2];
#pragma unroll
  for (int qb = 0; qb < 2; ++qb)
#pragma unroll
    for (int ks = 0; ks < 2; ++ks)
      qf[qb][ks] = *(const bf16x8*)&Qp[(size_t)(qw + qb * 16 + col) * HD +
                                       ks * 32 + g * 8];

  f32x4 zero4 = {0.f, 0.f, 0.f, 0.f};
  f32x4 o[2][4];
  float l8[2] = {0.f, 0.f};
#pragma unroll
  for (int qb = 0; qb < 2; ++qb)
#pragma unroll
    for (int nb = 0; nb < 4; ++nb) o[qb][nb] = zero4;

  const float SC = 0.18033688f;  // log2(e) / sqrt(64)
  int cbase = ((qw - 128) >> 6) << 6;

  for (int c = 0; c < 5; ++c) {
    int c0 = cbase + c * 64;
    if (c0 + 64 <= 0 || c0 >= SQ) continue;

    // S^T = K Q^T  (A = K: m = key, k = d;  B = Q: n = query)
    f32x4 s[4][2];
#pragma unroll
    for (int kb = 0; kb < 4; ++kb)
#pragma unroll
      for (int qb = 0; qb < 2; ++qb) s[kb][qb] = zero4;
#pragma unroll
    for (int ks = 0; ks < 2; ++ks) {
      bf16x8 kf[4];
#pragma unroll
      for (int kb = 0; kb < 4; ++kb) {
        int j = c0 + kb * 16 + col;
        us8 t = {0, 0, 0, 0, 0, 0, 0, 0};
        if ((unsigned)j < SQ)
          t = *(const us8*)&Kp[(size_t)j * HD + ks * 32 + g * 8];
        kf[kb] = as_bf(t);
      }
#pragma unroll
      for (int kb = 0; kb < 4; ++kb)
#pragma unroll
        for (int qb = 0; qb < 2; ++qb)
          s[kb][qb] = mfma16(kf[kb], qf[qb][ks], s[kb][qb]);
    }

    bool fullv = (c0 >= 0) && (c0 + 63 < SQ) && (c0 >= qw - 97) &&
                 (c0 + 63 <= qw + 128);
#pragma unroll
    for (int kb = 0; kb < 4; ++kb) {
#pragma unroll
      for (int qb = 0; qb < 2; ++qb) {
        float p[4];
#pragma unroll
        for (int r = 0; r < 4; ++r) {
          float e = __builtin_amdgcn_exp2f(s[kb][qb][r] * SC);
          if (!fullv) {
            int j = c0 + kb * 16 + g * 4 + r;
            int iq = qw + qb * 16 + col;
            bool ok = ((unsigned)j < SQ) && (iq - j <= WIN) && (j - iq <= WIN);
            e = ok ? e : 0.0f;
          }
          p[r] = e;
          l8[qb] += e;
        }
        union { __hip_bfloat162 h2[2]; us4v u4; } pk;
        pk.h2[0] = __float22bfloat162_rn(make_float2(p[0], p[1]));
        pk.h2[1] = __float22bfloat162_rn(make_float2(p[2], p[3]));
        *(us4v*)&Pw[(qb * 16 + col) * 72 + kb * 16 + g * 4] = pk.u4;
      }
    }

    // O += P V   (A = P: m = query, k = key; B = V^T: n = d, contiguous key)
#pragma unroll
    for (int ks = 0; ks < 2; ++ks) {
      bf16x8 pf[2], vf[4];
#pragma unroll
      for (int qb = 0; qb < 2; ++qb)
        pf[qb] = *(const bf16x8*)&Pw[(qb * 16 + col) * 72 + ks * 32 + g * 8];
      int kv = c0 + ks * 32 + g * 8;
#pragma unroll
      for (int nb = 0; nb < 4; ++nb) {
        us8 t = {0, 0, 0, 0, 0, 0, 0, 0};
        if ((unsigned)kv < SQ)
          t = *(const us8*)&Vt[(size_t)(nb * 16 + col) * SQ + kv];
        vf[nb] = as_bf(t);
      }
#pragma unroll
      for (int qb = 0; qb < 2; ++qb)
#pragma unroll
        for (int nb = 0; nb < 4; ++nb)
          o[qb][nb] = mfma16(pf[qb], vf[nb], o[qb][nb]);
    }
  }

  // denominators: lane(col,g) holds partial sum for q=col; reduce over g
#pragma unroll
  for (int qb = 0; qb < 2; ++qb) {
    l8[qb] += __shfl_xor(l8[qb], 16, 64);
    l8[qb] += __shfl_xor(l8[qb], 32, 64);
  }

#pragma unroll
  for (int qb = 0; qb < 2; ++qb)
#pragma unroll
    for (int r = 0; r < 4; ++r) {
      float inv = 1.0f / __shfl(l8[qb], g * 4 + r, 64);
      int iq = qw + qb * 16 + g * 4 + r;
      float* op = out + ((size_t)b * SQ + iq) * DM + h * HD;
#pragma unroll
      for (int nb = 0; nb < 4; ++nb) op[nb * 16 + col] = o[qb][nb][r] * inv;
    }
}

// ---------------------------------------------------------------------------
extern "C" void kernel_launch(void* const* d_in, const int* in_sizes, int n_in,
                              void* d_out, int out_size, void* d_ws,
                              size_t ws_size, hipStream_t stream) {
  const float* hs = (const float*)d_in[0];
  const float* Wq = (const float*)d_in[1];
  const float* bq = (const float*)d_in[2];
  const float* Wk = (const float*)d_in[3];
  const float* bk = (const float*)d_in[4];
  const float* Wv = (const float*)d_in[5];
  const float* bv = (const float*)d_in[6];
  float* out = (float*)d_out;
  char* ws = (char*)d_ws;

  // ws layout (bytes): Xb 16MB | Wt 6MB | Qh 16MB | Kh 16MB | Vt 16MB
  u16* Xb = (u16*)(ws);
  u16* Wt = (u16*)(ws + 16777216ULL);
  u16* Qh = (u16*)(ws + 23068672ULL);
  u16* Kh = (u16*)(ws + 39845888ULL);
  u16* Vt = (u16*)(ws + 56623104ULL);

  k_prep<<<dim3(11264), dim3(256), 0, stream>>>(hs, Xb, Wq, Wk, Wv, Wt);
  k_gemm<<<dim3(32, 12), dim3(512), 0, stream>>>(Xb, Wt, bq, bk, bv, Qh, Kh, Vt);
  k_attn<<<dim3(1024), dim3(256), 0, stream>>>(Qh, Kh, Vt, out);
}

// Round 7
// 195.979 us; speedup vs baseline: 1.1457x; 1.1457x over previous
//
#include <hip/hip_runtime.h>
#include <hip/hip_bf16.h>

// ---------------------------------------------------------------------------
// SlidingWindowAttention: fused QKV projection (bf16 MFMA GEMM) + windowed
// flash attention (bf16 MFMA, S^T trick).
// GEMM: 256x128 tile, 3-LDS-buffer ring (prefetch distance 2), BK=64,
// ONE barrier per K-tile: within a tile, staging (buf (t+2)%3) and reads
// (buf t%3) never touch the same buffer, and each wave's ds_reads are
// drained by its own MFMA lgkm wait before the barrier. The single
// end-of-tile barrier, preceded by vmcnt(6), publishes tile t+1 to all
// waves (round-2 lesson). Compiler is free to interleave/skew within the
// tile -> LDS reads and staging overlap MFMA across waves.
// Attn: T14 V-load hoist (issue V right after QK^T; softmax hides latency).
// Q,K stored head-major [b][h][s][d]; V stored transposed [b][h][d][s].
// B=4, S=2048, D=1024, H=16, hd=64, WINDOW=128.
// ---------------------------------------------------------------------------

#define NB 4
#define SQ 2048
#define NH 16
#define HD 64
#define DM 1024
#define WIN 128

typedef unsigned short u16;
typedef __bf16 bf16x8 __attribute__((ext_vector_type(8)));
typedef unsigned short us8 __attribute__((ext_vector_type(8)));
typedef unsigned short us4v __attribute__((ext_vector_type(4)));
typedef float f32x4 __attribute__((ext_vector_type(4)));

__device__ __forceinline__ u16 f2b(float f) {
  union { float f; unsigned u; } v; v.f = f;
  unsigned r = v.u + 0x7FFFu + ((v.u >> 16) & 1u);   // RNE
  return (u16)(r >> 16);
}

__device__ __forceinline__ bf16x8 as_bf(us8 v) {
  union { us8 a; bf16x8 b; } u; u.a = v; return u.b;
}

__device__ __forceinline__ f32x4 mfma16(bf16x8 a, bf16x8 b, f32x4 c) {
  return __builtin_amdgcn_mfma_f32_16x16x32_bf16(a, b, c, 0, 0, 0);
}

// async global->LDS, 16B per lane; LDS dest is wave-uniform base + lane*16
__device__ __forceinline__ void gl_lds16(const u16* g, u16* l) {
#if __has_builtin(__builtin_amdgcn_global_load_lds)
  __builtin_amdgcn_global_load_lds(
      (const __attribute__((address_space(1))) void*)g,
      (__attribute__((address_space(3))) void*)l, 16, 0, 0);
#else
  int lane = threadIdx.x & 63;
  *(us8*)(l + lane * 8) = *(const us8*)g;
#endif
}

// raw barrier with scheduler fences on both sides: no vmcnt(0)/lgkmcnt(0)
// drain; "memory" clobber keeps all memory ops on their side (rule 18).
#define MIDBAR()                                   \
  do {                                             \
    __builtin_amdgcn_sched_barrier(0);             \
    asm volatile("s_barrier" ::: "memory");        \
    __builtin_amdgcn_sched_barrier(0);             \
  } while (0)

// ---------------------------------------------------------------------------
// 1) prep: X fp32->bf16 (blocks 0..8191) ; W^T bf16 (blocks 8192..11263)
// ---------------------------------------------------------------------------
__global__ void k_prep(const float* __restrict__ X, u16* __restrict__ Xb,
                       const float* __restrict__ W0,
                       const float* __restrict__ W1,
                       const float* __restrict__ W2, u16* __restrict__ Wt) {
  int bx = blockIdx.x;
  int t = threadIdx.x;
  if (bx < 8192) {
    int idx = bx * 256 + t;
    float4 v = ((const float4*)X)[idx];
    us4v o = { f2b(v.x), f2b(v.y), f2b(v.z), f2b(v.w) };
    ((us4v*)Xb)[idx] = o;
    return;
  }
  int tb = bx - 8192;
  int mat = tb >> 10, rem = tb & 1023;
  const float* W = mat == 0 ? W0 : (mat == 1 ? W1 : W2);
  u16* dst = Wt + (size_t)mat * DM * DM;
  __shared__ float tile[32][33];
  int n0 = (rem & 31) * 32, k0 = (rem >> 5) * 32;
  int c = t & 31, r8 = t >> 5;
  for (int p = 0; p < 4; ++p) {
    int r = p * 8 + r8;
    tile[r][c] = W[(size_t)(k0 + r) * DM + n0 + c];
  }
  __syncthreads();
  for (int p = 0; p < 4; ++p) {
    int r = p * 8 + r8;
    dst[(size_t)(n0 + r) * DM + k0 + c] = f2b(tile[c][r]);
  }
}

// ---------------------------------------------------------------------------
// 2) GEMM: 256x128 tile, BK=64, 512 threads (8 waves, 4M x 2N, 64x64/wave).
//    3-buffer ring, ONE barrier per K-tile, vmcnt(6) before that barrier.
//    XOR-swizzled packed LDS (slot kg ^ (row&7)) -> conflict-free ds_read_b128.
//    Epilogues: mat 0/1 (Q,K) -> head-major [b][h][s][d];
//               mat 2  (V)   -> transposed [b][h][d][s] (8B vector stores).
// ---------------------------------------------------------------------------
__global__ __launch_bounds__(512, 2) void k_gemm(
    const u16* __restrict__ Xb, const u16* __restrict__ Wt,
    const float* __restrict__ bq, const float* __restrict__ bk,
    const float* __restrict__ bv,
    u16* __restrict__ Qh, u16* __restrict__ Kh, u16* __restrict__ VtG) {
  int mat = blockIdx.y >> 3;
  int n0 = (blockIdx.y & 7) * 128;
  int m0 = blockIdx.x * 256;
  const u16* Bw = Wt + (size_t)mat * DM * DM;
  const float* bias = mat == 0 ? bq : (mat == 1 ? bk : bv);

  // ring of 3 K-tiles: A 256x64 + B 128x64 bf16 each = 144 KiB total
  __shared__ u16 As[3][256 * 64];
  __shared__ u16 Bs[3][128 * 64];

  int tid = threadIdx.x;
  int lane = tid & 63, wave = tid >> 6;      // wave 0..7
  int wm = wave >> 1, wn = wave & 1;         // 4M x 2N
  int col = lane & 15, g = lane >> 4;

  // staging: row = base + i*8 + (lane>>3), slot = (lane&7) ^ (row&7)
  int srow = lane >> 3;
  int skg = (lane & 7) ^ srow;
  const u16* gA = Xb + (size_t)(m0 + wave * 32 + srow) * DM + skg * 8;
  const u16* gB = Bw + (size_t)(n0 + wave * 16 + srow) * DM + skg * 8;

  f32x4 zero4 = {0.f, 0.f, 0.f, 0.f};
  f32x4 acc[4][4];
  for (int i = 0; i < 4; ++i)
    for (int j = 0; j < 4; ++j) acc[i][j] = zero4;

#define STAGE_A(kt, bi, i)                                              \
  gl_lds16(gA + (size_t)(i) * 8 * DM + (kt) * 64,                       \
           &As[bi][(wave * 32 + (i) * 8) * 64])
#define STAGE_B(kt, bi, j)                                              \
  gl_lds16(gB + (size_t)(j) * 8 * DM + (kt) * 64,                       \
           &Bs[bi][(wave * 16 + (j) * 8) * 64])

// one K-tile, ONE barrier: {reads half0 | stage 3} MFMA0 {reads half1 |
// stage 3} MFMA1 vmcnt barrier. Hazard argument in header comment.
// DO: literal 0/1, stage tile kt into buffer b2.
// VMST: counted vmcnt before the barrier (covers the next tile's loads).
#define KTILE(bi, b2, kt, DO, VMST)                                      \
  do {                                                                   \
    bf16x8 bfl[2][4], afl0[2][2], afl1[2][2];                            \
    _Pragma("unroll") for (int ks = 0; ks < 2; ++ks) {                   \
      int kg = ((ks * 4 + g) ^ (col & 7)) * 8;                           \
      _Pragma("unroll") for (int ni = 0; ni < 4; ++ni)                   \
        bfl[ks][ni] =                                                    \
            *(const bf16x8*)&Bs[bi][(wn * 64 + ni * 16 + col) * 64 + kg];\
      _Pragma("unroll") for (int mi = 0; mi < 2; ++mi)                   \
        afl0[ks][mi] =                                                   \
            *(const bf16x8*)&As[bi][(wm * 64 + mi * 16 + col) * 64 + kg];\
    }                                                                    \
    if (DO) {                                                            \
      STAGE_A(kt, b2, 0); STAGE_A(kt, b2, 1); STAGE_A(kt, b2, 2);        \
    }                                                                    \
    __builtin_amdgcn_s_setprio(1);                                       \
    _Pragma("unroll") for (int ks = 0; ks < 2; ++ks)                     \
      _Pragma("unroll") for (int mi = 0; mi < 2; ++mi)                   \
        _Pragma("unroll") for (int ni = 0; ni < 4; ++ni)                 \
          acc[mi][ni] = mfma16(afl0[ks][mi], bfl[ks][ni], acc[mi][ni]);  \
    __builtin_amdgcn_s_setprio(0);                                       \
    _Pragma("unroll") for (int ks = 0; ks < 2; ++ks) {                   \
      int kg = ((ks * 4 + g) ^ (col & 7)) * 8;                           \
      _Pragma("unroll") for (int mi = 0; mi < 2; ++mi)                   \
        afl1[ks][mi] = *(const bf16x8*)&As[bi][(wm * 64 + 32 + mi * 16 + \
                                                col) * 64 + kg];         \
    }                                                                    \
    if (DO) {                                                            \
      STAGE_A(kt, b2, 3); STAGE_B(kt, b2, 0); STAGE_B(kt, b2, 1);        \
    }                                                                    \
    __builtin_amdgcn_s_setprio(1);                                       \
    _Pragma("unroll") for (int ks = 0; ks < 2; ++ks)                     \
      _Pragma("unroll") for (int mi = 0; mi < 2; ++mi)                   \
        _Pragma("unroll") for (int ni = 0; ni < 4; ++ni)                 \
          acc[2 + mi][ni] =                                              \
              mfma16(afl1[ks][mi], bfl[ks][ni], acc[2 + mi][ni]);        \
    __builtin_amdgcn_s_setprio(0);                                       \
    VMST;                                                                \
    MIDBAR(); /* publish: every wave's vmcnt covers the next tile */     \
  } while (0)

  // prologue: tiles 0,1 fully staged; vmcnt(6) = own tile-0 landed; barrier
  // publishes it to all waves before any tile-0 read.
  STAGE_A(0, 0, 0); STAGE_A(0, 0, 1); STAGE_A(0, 0, 2); STAGE_A(0, 0, 3);
  STAGE_B(0, 0, 0); STAGE_B(0, 0, 1);
  __builtin_amdgcn_sched_barrier(0);
  STAGE_A(1, 1, 0); STAGE_A(1, 1, 1); STAGE_A(1, 1, 2); STAGE_A(1, 1, 3);
  STAGE_B(1, 1, 0); STAGE_B(1, 1, 1);
  asm volatile("s_waitcnt vmcnt(6)" ::: "memory");
  MIDBAR();

  // main loop: tiles 0..13, staging t+2 into ring slot (t+2)%3.
  // end-of-iter vmcnt(6): 12 outstanding (t+1:6, t+2:6) -> tile t+1 landed.
  int cb = 0, sb = 2;
  for (int t = 0; t < 14; ++t) {
    KTILE(cb, sb, t + 2, 1,
          asm volatile("s_waitcnt vmcnt(6)" ::: "memory"));
    cb = cb == 2 ? 0 : cb + 1;
    sb = sb == 2 ? 0 : sb + 1;
  }
  // tail: tile 14 (buf 2) with vmcnt(0) covering tile 15; tile 15 (buf 0).
  KTILE(2, 0, 0, 0, asm volatile("s_waitcnt vmcnt(0)" ::: "memory"));
  KTILE(0, 0, 0, 0, ((void)0));

#undef KTILE
#undef STAGE_A
#undef STAGE_B

  float bvv[4];
  for (int ni = 0; ni < 4; ++ni)
    bvv[ni] = bias[n0 + wn * 64 + ni * 16 + col];

  if (mat < 2) {
    // head-major: addr = ((b*NH + h)*SQ + s)*HD + d
    u16* C = mat == 0 ? Qh : Kh;
    for (int mi = 0; mi < 4; ++mi) {
      int m = m0 + wm * 64 + mi * 16 + g * 4;
      int bb = m >> 11, s0 = m & 2047;
      for (int r = 0; r < 4; ++r) {
        size_t base = ((size_t)(bb * NH) * SQ + (s0 + r)) * HD;
        for (int ni = 0; ni < 4; ++ni) {
          int n = n0 + wn * 64 + ni * 16 + col;
          int h = n >> 6, d = n & 63;
          C[base + (size_t)h * SQ * HD + d] = f2b(acc[mi][ni][r] + bvv[ni]);
        }
      }
    }
  } else {
    // V^T: [b][h][d][s]; rows of C are consecutive tokens s -> 8B stores
    for (int mi = 0; mi < 4; ++mi) {
      int m = m0 + wm * 64 + mi * 16 + g * 4;
      int bb = m >> 11, s0 = m & 2047;
      for (int ni = 0; ni < 4; ++ni) {
        int n = n0 + wn * 64 + ni * 16 + col;
        us4v ov = { f2b(acc[mi][ni][0] + bvv[ni]), f2b(acc[mi][ni][1] + bvv[ni]),
                    f2b(acc[mi][ni][2] + bvv[ni]), f2b(acc[mi][ni][3] + bvv[ni]) };
        *(us4v*)&VtG[((size_t)(bb * 1024 + n)) * SQ + s0] = ov;
      }
    }
  }
}

// ---------------------------------------------------------------------------
// 3) Windowed flash attention. Block = 4 waves; each wave owns 32 queries of
//    one (b,h), loops over 5 key-chunks of 64. S^T = K*Q^T so each lane holds
//    4 consecutive keys -> vectorized P stores. All global loads line-exact
//    (Q,K head-major; V^T key-contiguous). No __syncthreads.
//    T14: V loads issued right after QK^T (kf regs dead there); softmax
//    VALU section hides the V global latency.
// ---------------------------------------------------------------------------
__global__ __launch_bounds__(256) void k_attn(
    const u16* __restrict__ Qh, const u16* __restrict__ Kh,
    const u16* __restrict__ VtG, float* __restrict__ out) {
  int bid = blockIdx.x;
  int b = bid >> 8;
  int h = (bid >> 4) & 15;
  int q0 = (bid & 15) << 7;
  int tid = threadIdx.x, lane = tid & 63, wave = tid >> 6;
  int col = lane & 15, g = lane >> 4;
  int qw = q0 + wave * 32;

  __shared__ u16 Ps[4][32 * 72];
  u16* Pw = Ps[wave];

  const u16* Qp = Qh + (size_t)(b * NH + h) * SQ * HD;
  const u16* Kp = Kh + (size_t)(b * NH + h) * SQ * HD;
  const u16* Vt = VtG + (size_t)(b * 1024 + h * 64) * SQ;

  // Q fragments (B operand: lane col = query, contiguous d)
  bf16x8 qf[2][2];
#pragma unroll
  for (int qb = 0; qb < 2; ++qb)
#pragma unroll
    for (int ks = 0; ks < 2; ++ks)
      qf[qb][ks] = *(const bf16x8*)&Qp[(size_t)(qw + qb * 16 + col) * HD +
                                       ks * 32 + g * 8];

  f32x4 zero4 = {0.f, 0.f, 0.f, 0.f};
  f32x4 o[2][4];
  float l8[2] = {0.f, 0.f};
#pragma unroll
  for (int qb = 0; qb < 2; ++qb)
#pragma unroll
    for (int nb = 0; nb < 4; ++nb) o[qb][nb] = zero4;

  const float SC = 0.18033688f;  // log2(e) / sqrt(64)
  int cbase = ((qw - 128) >> 6) << 6;

  for (int c = 0; c < 5; ++c) {
    int c0 = cbase + c * 64;
    if (c0 + 64 <= 0 || c0 >= SQ) continue;

    // S^T = K Q^T  (A = K: m = key, k = d;  B = Q: n = query)
    f32x4 s[4][2];
#pragma unroll
    for (int kb = 0; kb < 4; ++kb)
#pragma unroll
      for (int qb = 0; qb < 2; ++qb) s[kb][qb] = zero4;
#pragma unroll
    for (int ks = 0; ks < 2; ++ks) {
      bf16x8 kf[4];
#pragma unroll
      for (int kb = 0; kb < 4; ++kb) {
        int j = c0 + kb * 16 + col;
        us8 t = {0, 0, 0, 0, 0, 0, 0, 0};
        if ((unsigned)j < SQ)
          t = *(const us8*)&Kp[(size_t)j * HD + ks * 32 + g * 8];
        kf[kb] = as_bf(t);
      }
#pragma unroll
      for (int kb = 0; kb < 4; ++kb)
#pragma unroll
        for (int qb = 0; qb < 2; ++qb)
          s[kb][qb] = mfma16(kf[kb], qf[qb][ks], s[kb][qb]);
    }

    // T14: issue V loads now (consumed after softmax; kf regs reusable)
    us8 vraw[2][4];
#pragma unroll
    for (int ks = 0; ks < 2; ++ks) {
      int kv = c0 + ks * 32 + g * 8;
      bool okv = (unsigned)kv < SQ;
#pragma unroll
      for (int nb = 0; nb < 4; ++nb) {
        us8 t = {0, 0, 0, 0, 0, 0, 0, 0};
        if (okv) t = *(const us8*)&Vt[(size_t)(nb * 16 + col) * SQ + kv];
        vraw[ks][nb] = t;
      }
    }

    bool fullv = (c0 >= 0) && (c0 + 63 < SQ) && (c0 >= qw - 97) &&
                 (c0 + 63 <= qw + 128);
#pragma unroll
    for (int kb = 0; kb < 4; ++kb) {
#pragma unroll
      for (int qb = 0; qb < 2; ++qb) {
        float p[4];
#pragma unroll
        for (int r = 0; r < 4; ++r) {
          float e = __builtin_amdgcn_exp2f(s[kb][qb][r] * SC);
          if (!fullv) {
            int j = c0 + kb * 16 + g * 4 + r;
            int iq = qw + qb * 16 + col;
            bool ok = ((unsigned)j < SQ) && (iq - j <= WIN) && (j - iq <= WIN);
            e = ok ? e : 0.0f;
          }
          p[r] = e;
          l8[qb] += e;
        }
        union { __hip_bfloat162 h2[2]; us4v u4; } pk;
        pk.h2[0] = __float22bfloat162_rn(make_float2(p[0], p[1]));
        pk.h2[1] = __float22bfloat162_rn(make_float2(p[2], p[3]));
        *(us4v*)&Pw[(qb * 16 + col) * 72 + kb * 16 + g * 4] = pk.u4;
      }
    }

    // O += P V   (A = P: m = query, k = key; B = V^T: n = d, contiguous key)
#pragma unroll
    for (int ks = 0; ks < 2; ++ks) {
      bf16x8 pf[2];
#pragma unroll
      for (int qb = 0; qb < 2; ++qb)
        pf[qb] = *(const bf16x8*)&Pw[(qb * 16 + col) * 72 + ks * 32 + g * 8];
#pragma unroll
      for (int qb = 0; qb < 2; ++qb)
#pragma unroll
        for (int nb = 0; nb < 4; ++nb)
          o[qb][nb] = mfma16(pf[qb], as_bf(vraw[ks][nb]), o[qb][nb]);
    }
  }

  // denominators: lane(col,g) holds partial sum for q=col; reduce over g
#pragma unroll
  for (int qb = 0; qb < 2; ++qb) {
    l8[qb] += __shfl_xor(l8[qb], 16, 64);
    l8[qb] += __shfl_xor(l8[qb], 32, 64);
  }

#pragma unroll
  for (int qb = 0; qb < 2; ++qb)
#pragma unroll
    for (int r = 0; r < 4; ++r) {
      float inv = 1.0f / __shfl(l8[qb], g * 4 + r, 64);
      int iq = qw + qb * 16 + g * 4 + r;
      float* op = out + ((size_t)b * SQ + iq) * DM + h * HD;
#pragma unroll
      for (int nb = 0; nb < 4; ++nb) op[nb * 16 + col] = o[qb][nb][r] * inv;
    }
}

// ---------------------------------------------------------------------------
extern "C" void kernel_launch(void* const* d_in, const int* in_sizes, int n_in,
                              void* d_out, int out_size, void* d_ws,
                              size_t ws_size, hipStream_t stream) {
  const float* hs = (const float*)d_in[0];
  const float* Wq = (const float*)d_in[1];
  const float* bq = (const float*)d_in[2];
  const float* Wk = (const float*)d_in[3];
  const float* bk = (const float*)d_in[4];
  const float* Wv = (const float*)d_in[5];
  const float* bv = (const float*)d_in[6];
  float* out = (float*)d_out;
  char* ws = (char*)d_ws;

  // ws layout (bytes): Xb 16MB | Wt 6MB | Qh 16MB | Kh 16MB | Vt 16MB
  u16* Xb = (u16*)(ws);
  u16* Wt = (u16*)(ws + 16777216ULL);
  u16* Qh = (u16*)(ws + 23068672ULL);
  u16* Kh = (u16*)(ws + 39845888ULL);
  u16* Vt = (u16*)(ws + 56623104ULL);

  k_prep<<<dim3(11264), dim3(256), 0, stream>>>(hs, Xb, Wq, Wk, Wv, Wt);
  k_gemm<<<dim3(32, 24), dim3(512), 0, stream>>>(Xb, Wt, bq, bk, bv, Qh, Kh, Vt);
  k_attn<<<dim3(1024), dim3(256), 0, stream>>>(Qh, Kh, Vt, out);
}

// Round 8
// 194.924 us; speedup vs baseline: 1.1519x; 1.0054x over previous
//
#include <hip/hip_runtime.h>
#include <hip/hip_bf16.h>

// ---------------------------------------------------------------------------
// SlidingWindowAttention: fused QKV projection (bf16 MFMA GEMM) + windowed
// flash attention (bf16 MFMA, S^T trick).
// GEMM: 128x128 tile, ring-2 (double-buffer) LDS = 64 KiB -> 2 blocks/CU so
// co-resident blocks overlap DS-read phases with MFMA phases (m114). One raw
// barrier per K-tile; stage-next issued between ds_reads and MFMAs; vmcnt(0)
// before the publish barrier (round-2 ordering rule: reads of tile t follow a
// barrier that every wave reached after a vmcnt covering tile t).
// Attn: T14 V-load hoist (issue V right after QK^T; softmax hides latency).
// Q,K stored head-major [b][h][s][d]; V stored transposed [b][h][d][s].
// B=4, S=2048, D=1024, H=16, hd=64, WINDOW=128.
// ---------------------------------------------------------------------------

#define NB 4
#define SQ 2048
#define NH 16
#define HD 64
#define DM 1024
#define WIN 128

typedef unsigned short u16;
typedef __bf16 bf16x8 __attribute__((ext_vector_type(8)));
typedef unsigned short us8 __attribute__((ext_vector_type(8)));
typedef unsigned short us4v __attribute__((ext_vector_type(4)));
typedef float f32x4 __attribute__((ext_vector_type(4)));

__device__ __forceinline__ u16 f2b(float f) {
  union { float f; unsigned u; } v; v.f = f;
  unsigned r = v.u + 0x7FFFu + ((v.u >> 16) & 1u);   // RNE
  return (u16)(r >> 16);
}

__device__ __forceinline__ bf16x8 as_bf(us8 v) {
  union { us8 a; bf16x8 b; } u; u.a = v; return u.b;
}

__device__ __forceinline__ f32x4 mfma16(bf16x8 a, bf16x8 b, f32x4 c) {
  return __builtin_amdgcn_mfma_f32_16x16x32_bf16(a, b, c, 0, 0, 0);
}

// async global->LDS, 16B per lane; LDS dest is wave-uniform base + lane*16
__device__ __forceinline__ void gl_lds16(const u16* g, u16* l) {
#if __has_builtin(__builtin_amdgcn_global_load_lds)
  __builtin_amdgcn_global_load_lds(
      (const __attribute__((address_space(1))) void*)g,
      (__attribute__((address_space(3))) void*)l, 16, 0, 0);
#else
  int lane = threadIdx.x & 63;
  *(us8*)(l + lane * 8) = *(const us8*)g;
#endif
}

// raw barrier with scheduler fences on both sides: no vmcnt(0)/lgkmcnt(0)
// drain; "memory" clobber keeps all memory ops on their side (rule 18).
#define MIDBAR()                                   \
  do {                                             \
    __builtin_amdgcn_sched_barrier(0);             \
    asm volatile("s_barrier" ::: "memory");        \
    __builtin_amdgcn_sched_barrier(0);             \
  } while (0)

// ---------------------------------------------------------------------------
// 1) prep: X fp32->bf16 (blocks 0..8191) ; W^T bf16 (blocks 8192..11263)
// ---------------------------------------------------------------------------
__global__ void k_prep(const float* __restrict__ X, u16* __restrict__ Xb,
                       const float* __restrict__ W0,
                       const float* __restrict__ W1,
                       const float* __restrict__ W2, u16* __restrict__ Wt) {
  int bx = blockIdx.x;
  int t = threadIdx.x;
  if (bx < 8192) {
    int idx = bx * 256 + t;
    float4 v = ((const float4*)X)[idx];
    us4v o = { f2b(v.x), f2b(v.y), f2b(v.z), f2b(v.w) };
    ((us4v*)Xb)[idx] = o;
    return;
  }
  int tb = bx - 8192;
  int mat = tb >> 10, rem = tb & 1023;
  const float* W = mat == 0 ? W0 : (mat == 1 ? W1 : W2);
  u16* dst = Wt + (size_t)mat * DM * DM;
  __shared__ float tile[32][33];
  int n0 = (rem & 31) * 32, k0 = (rem >> 5) * 32;
  int c = t & 31, r8 = t >> 5;
  for (int p = 0; p < 4; ++p) {
    int r = p * 8 + r8;
    tile[r][c] = W[(size_t)(k0 + r) * DM + n0 + c];
  }
  __syncthreads();
  for (int p = 0; p < 4; ++p) {
    int r = p * 8 + r8;
    dst[(size_t)(n0 + r) * DM + k0 + c] = f2b(tile[c][r]);
  }
}

// ---------------------------------------------------------------------------
// 2) GEMM: 128x128 tile, BK=64, 256 threads (4 waves, 2M x 2N, 64x64/wave).
//    Ring-2, ONE barrier per K-tile, vmcnt(0) before that barrier.
//    XOR-swizzled packed LDS (slot kg ^ (row&7)) -> conflict-free ds_read_b128.
//    Epilogues: mat 0/1 (Q,K) -> head-major [b][h][s][d];
//               mat 2  (V)   -> transposed [b][h][d][s] (8B vector stores).
// ---------------------------------------------------------------------------
__global__ __launch_bounds__(256, 2) void k_gemm(
    const u16* __restrict__ Xb, const u16* __restrict__ Wt,
    const float* __restrict__ bq, const float* __restrict__ bk,
    const float* __restrict__ bv,
    u16* __restrict__ Qh, u16* __restrict__ Kh, u16* __restrict__ VtG) {
  int mat = blockIdx.y >> 3;
  int n0 = (blockIdx.y & 7) * 128;
  int m0 = blockIdx.x * 128;
  const u16* Bw = Wt + (size_t)mat * DM * DM;
  const float* bias = mat == 0 ? bq : (mat == 1 ? bk : bv);

  // double buffer: (A 128x64 + B 128x64) bf16 x2 = 64 KiB -> 2 blocks/CU
  __shared__ u16 As[2][128 * 64];
  __shared__ u16 Bs[2][128 * 64];

  int tid = threadIdx.x;
  int lane = tid & 63, wave = tid >> 6;      // wave 0..3
  int wm = wave >> 1, wn = wave & 1;         // 2M x 2N, 64x64 per wave
  int col = lane & 15, g = lane >> 4;

  // staging: row = wave*32 + i*8 + (lane>>3), slot = (lane&7) ^ (row&7)
  int srow = lane >> 3;
  int skg = (lane & 7) ^ srow;
  const u16* gA = Xb + (size_t)(m0 + wave * 32 + srow) * DM + skg * 8;
  const u16* gB = Bw + (size_t)(n0 + wave * 32 + srow) * DM + skg * 8;

  f32x4 zero4 = {0.f, 0.f, 0.f, 0.f};
  f32x4 acc[4][4];
  for (int i = 0; i < 4; ++i)
    for (int j = 0; j < 4; ++j) acc[i][j] = zero4;

  // stage K-tile kt into buffer bi: 4 A-calls + 4 B-calls, 8 rows each
#define STAGE8(kt, bi)                                                  \
  do {                                                                  \
    _Pragma("unroll") for (int i = 0; i < 4; ++i)                       \
      gl_lds16(gA + (size_t)i * 8 * DM + (kt) * 64,                     \
               &As[bi][(wave * 32 + i * 8) * 64]);                      \
    _Pragma("unroll") for (int i = 0; i < 4; ++i)                       \
      gl_lds16(gB + (size_t)i * 8 * DM + (kt) * 64,                     \
               &Bs[bi][(wave * 32 + i * 8) * 64]);                      \
  } while (0)

  // prologue: tile 0 -> buf 0; publish before any read
  STAGE8(0, 0);
  asm volatile("s_waitcnt vmcnt(0)" ::: "memory");
  MIDBAR();

  for (int t = 0; t < 16; ++t) {
    int cur = t & 1, nxt = cur ^ 1;
    bf16x8 afl[2][4], bfl[2][4];
#pragma unroll
    for (int ks = 0; ks < 2; ++ks) {
      int kg = ((ks * 4 + g) ^ (col & 7)) * 8;
#pragma unroll
      for (int mi = 0; mi < 4; ++mi)
        afl[ks][mi] =
            *(const bf16x8*)&As[cur][(wm * 64 + mi * 16 + col) * 64 + kg];
#pragma unroll
      for (int ni = 0; ni < 4; ++ni)
        bfl[ks][ni] =
            *(const bf16x8*)&Bs[cur][(wn * 64 + ni * 16 + col) * 64 + kg];
    }
    if (t < 15) STAGE8(t + 1, nxt);   // overlaps the MFMA cluster below
    __builtin_amdgcn_s_setprio(1);
#pragma unroll
    for (int ks = 0; ks < 2; ++ks)
#pragma unroll
      for (int mi = 0; mi < 4; ++mi)
#pragma unroll
        for (int ni = 0; ni < 4; ++ni)
          acc[mi][ni] = mfma16(afl[ks][mi], bfl[ks][ni], acc[mi][ni]);
    __builtin_amdgcn_s_setprio(0);
    if (t < 15) asm volatile("s_waitcnt vmcnt(0)" ::: "memory");
    MIDBAR();  // publish: every wave's staged rows of tile t+1 landed
  }

#undef STAGE8

  float bvv[4];
  for (int ni = 0; ni < 4; ++ni)
    bvv[ni] = bias[n0 + wn * 64 + ni * 16 + col];

  if (mat < 2) {
    // head-major: addr = ((b*NH + h)*SQ + s)*HD + d
    u16* C = mat == 0 ? Qh : Kh;
    for (int mi = 0; mi < 4; ++mi) {
      int m = m0 + wm * 64 + mi * 16 + g * 4;
      int bb = m >> 11, s0 = m & 2047;
      for (int r = 0; r < 4; ++r) {
        size_t base = ((size_t)(bb * NH) * SQ + (s0 + r)) * HD;
        for (int ni = 0; ni < 4; ++ni) {
          int n = n0 + wn * 64 + ni * 16 + col;
          int h = n >> 6, d = n & 63;
          C[base + (size_t)h * SQ * HD + d] = f2b(acc[mi][ni][r] + bvv[ni]);
        }
      }
    }
  } else {
    // V^T: [b][h][d][s]; rows of C are consecutive tokens s -> 8B stores
    for (int mi = 0; mi < 4; ++mi) {
      int m = m0 + wm * 64 + mi * 16 + g * 4;
      int bb = m >> 11, s0 = m & 2047;
      for (int ni = 0; ni < 4; ++ni) {
        int n = n0 + wn * 64 + ni * 16 + col;
        us4v ov = { f2b(acc[mi][ni][0] + bvv[ni]), f2b(acc[mi][ni][1] + bvv[ni]),
                    f2b(acc[mi][ni][2] + bvv[ni]), f2b(acc[mi][ni][3] + bvv[ni]) };
        *(us4v*)&VtG[((size_t)(bb * 1024 + n)) * SQ + s0] = ov;
      }
    }
  }
}

// ---------------------------------------------------------------------------
// 3) Windowed flash attention. Block = 4 waves; each wave owns 32 queries of
//    one (b,h), loops over 5 key-chunks of 64. S^T = K*Q^T so each lane holds
//    4 consecutive keys -> vectorized P stores. All global loads line-exact
//    (Q,K head-major; V^T key-contiguous). No __syncthreads.
//    T14: V loads issued right after QK^T (kf regs dead there); softmax
//    VALU section hides the V global latency.
// ---------------------------------------------------------------------------
__global__ __launch_bounds__(256) void k_attn(
    const u16* __restrict__ Qh, const u16* __restrict__ Kh,
    const u16* __restrict__ VtG, float* __restrict__ out) {
  int bid = blockIdx.x;
  int b = bid >> 8;
  int h = (bid >> 4) & 15;
  int q0 = (bid & 15) << 7;
  int tid = threadIdx.x, lane = tid & 63, wave = tid >> 6;
  int col = lane & 15, g = lane >> 4;
  int qw = q0 + wave * 32;

  __shared__ u16 Ps[4][32 * 72];
  u16* Pw = Ps[wave];

  const u16* Qp = Qh + (size_t)(b * NH + h) * SQ * HD;
  const u16* Kp = Kh + (size_t)(b * NH + h) * SQ * HD;
  const u16* Vt = VtG + (size_t)(b * 1024 + h * 64) * SQ;

  // Q fragments (B operand: lane col = query, contiguous d)
  bf16x8 qf[2][2];
#pragma unroll
  for (int qb = 0; qb < 2; ++qb)
#pragma unroll
    for (int ks = 0; ks < 2; ++ks)
      qf[qb][ks] = *(const bf16x8*)&Qp[(size_t)(qw + qb * 16 + col) * HD +
                                       ks * 32 + g * 8];

  f32x4 zero4 = {0.f, 0.f, 0.f, 0.f};
  f32x4 o[2][4];
  float l8[2] = {0.f, 0.f};
#pragma unroll
  for (int qb = 0; qb < 2; ++qb)
#pragma unroll
    for (int nb = 0; nb < 4; ++nb) o[qb][nb] = zero4;

  const float SC = 0.18033688f;  // log2(e) / sqrt(64)
  int cbase = ((qw - 128) >> 6) << 6;

  for (int c = 0; c < 5; ++c) {
    int c0 = cbase + c * 64;
    if (c0 + 64 <= 0 || c0 >= SQ) continue;

    // S^T = K Q^T  (A = K: m = key, k = d;  B = Q: n = query)
    f32x4 s[4][2];
#pragma unroll
    for (int kb = 0; kb < 4; ++kb)
#pragma unroll
      for (int qb = 0; qb < 2; ++qb) s[kb][qb] = zero4;
#pragma unroll
    for (int ks = 0; ks < 2; ++ks) {
      bf16x8 kf[4];
#pragma unroll
      for (int kb = 0; kb < 4; ++kb) {
        int j = c0 + kb * 16 + col;
        us8 t = {0, 0, 0, 0, 0, 0, 0, 0};
        if ((unsigned)j < SQ)
          t = *(const us8*)&Kp[(size_t)j * HD + ks * 32 + g * 8];
        kf[kb] = as_bf(t);
      }
#pragma unroll
      for (int kb = 0; kb < 4; ++kb)
#pragma unroll
        for (int qb = 0; qb < 2; ++qb)
          s[kb][qb] = mfma16(kf[kb], qf[qb][ks], s[kb][qb]);
    }

    // T14: issue V loads now (consumed after softmax; kf regs reusable)
    us8 vraw[2][4];
#pragma unroll
    for (int ks = 0; ks < 2; ++ks) {
      int kv = c0 + ks * 32 + g * 8;
      bool okv = (unsigned)kv < SQ;
#pragma unroll
      for (int nb = 0; nb < 4; ++nb) {
        us8 t = {0, 0, 0, 0, 0, 0, 0, 0};
        if (okv) t = *(const us8*)&Vt[(size_t)(nb * 16 + col) * SQ + kv];
        vraw[ks][nb] = t;
      }
    }

    bool fullv = (c0 >= 0) && (c0 + 63 < SQ) && (c0 >= qw - 97) &&
                 (c0 + 63 <= qw + 128);
#pragma unroll
    for (int kb = 0; kb < 4; ++kb) {
#pragma unroll
      for (int qb = 0; qb < 2; ++qb) {
        float p[4];
#pragma unroll
        for (int r = 0; r < 4; ++r) {
          float e = __builtin_amdgcn_exp2f(s[kb][qb][r] * SC);
          if (!fullv) {
            int j = c0 + kb * 16 + g * 4 + r;
            int iq = qw + qb * 16 + col;
            bool ok = ((unsigned)j < SQ) && (iq - j <= WIN) && (j - iq <= WIN);
            e = ok ? e : 0.0f;
          }
          p[r] = e;
          l8[qb] += e;
        }
        union { __hip_bfloat162 h2[2]; us4v u4; } pk;
        pk.h2[0] = __float22bfloat162_rn(make_float2(p[0], p[1]));
        pk.h2[1] = __float22bfloat162_rn(make_float2(p[2], p[3]));
        *(us4v*)&Pw[(qb * 16 + col) * 72 + kb * 16 + g * 4] = pk.u4;
      }
    }

    // O += P V   (A = P: m = query, k = key; B = V^T: n = d, contiguous key)
#pragma unroll
    for (int ks = 0; ks < 2; ++ks) {
      bf16x8 pf[2];
#pragma unroll
      for (int qb = 0; qb < 2; ++qb)
        pf[qb] = *(const bf16x8*)&Pw[(qb * 16 + col) * 72 + ks * 32 + g * 8];
#pragma unroll
      for (int qb = 0; qb < 2; ++qb)
#pragma unroll
        for (int nb = 0; nb < 4; ++nb)
          o[qb][nb] = mfma16(pf[qb], as_bf(vraw[ks][nb]), o[qb][nb]);
    }
  }

  // denominators: lane(col,g) holds partial sum for q=col; reduce over g
#pragma unroll
  for (int qb = 0; qb < 2; ++qb) {
    l8[qb] += __shfl_xor(l8[qb], 16, 64);
    l8[qb] += __shfl_xor(l8[qb], 32, 64);
  }

#pragma unroll
  for (int qb = 0; qb < 2; ++qb)
#pragma unroll
    for (int r = 0; r < 4; ++r) {
      float inv = 1.0f / __shfl(l8[qb], g * 4 + r, 64);
      int iq = qw + qb * 16 + g * 4 + r;
      float* op = out + ((size_t)b * SQ + iq) * DM + h * HD;
#pragma unroll
      for (int nb = 0; nb < 4; ++nb) op[nb * 16 + col] = o[qb][nb][r] * inv;
    }
}

// ---------------------------------------------------------------------------
extern "C" void kernel_launch(void* const* d_in, const int* in_sizes, int n_in,
                              void* d_out, int out_size, void* d_ws,
                              size_t ws_size, hipStream_t stream) {
  const float* hs = (const float*)d_in[0];
  const float* Wq = (const float*)d_in[1];
  const float* bq = (const float*)d_in[2];
  const float* Wk = (const float*)d_in[3];
  const float* bk = (const float*)d_in[4];
  const float* Wv = (const float*)d_in[5];
  const float* bv = (const float*)d_in[6];
  float* out = (float*)d_out;
  char* ws = (char*)d_ws;

  // ws layout (bytes): Xb 16MB | Wt 6MB | Qh 16MB | Kh 16MB | Vt 16MB
  u16* Xb = (u16*)(ws);
  u16* Wt = (u16*)(ws + 16777216ULL);
  u16* Qh = (u16*)(ws + 23068672ULL);
  u16* Kh = (u16*)(ws + 39845888ULL);
  u16* Vt = (u16*)(ws + 56623104ULL);

  k_prep<<<dim3(11264), dim3(256), 0, stream>>>(hs, Xb, Wq, Wk, Wv, Wt);
  k_gemm<<<dim3(64, 24), dim3(256), 0, stream>>>(Xb, Wt, bq, bk, bv, Qh, Kh, Vt);
  k_attn<<<dim3(1024), dim3(256), 0, stream>>>(Qh, Kh, Vt, out);
}

// Round 9
// 193.633 us; speedup vs baseline: 1.1596x; 1.0067x over previous
//
#include <hip/hip_runtime.h>
#include <hip/hip_bf16.h>

// ---------------------------------------------------------------------------
// SlidingWindowAttention: fused QKV projection (bf16 MFMA GEMM) + windowed
// flash attention (bf16 MFMA, S^T trick).
// GEMM: 128x128 tile, double-buffer LDS (64 KiB -> 2 blocks/CU), one raw
// barrier per K-tile, vmcnt(0) before the publish barrier (round-8, 57 us,
// ~900 TF = m97-structure ceiling; parked).
// Attn round-9: T1 XCD-aware block swizzle (all 16 q-tiles of a (b,h) on one
// XCD -> K/V window stays L2-resident, kills cross-XCD refetch of the ~655MB
// raw load stream) + T5 setprio around QK^T / PV MFMA clusters (m191).
// Q,K stored head-major [b][h][s][d]; V stored transposed [b][h][d][s].
// B=4, S=2048, D=1024, H=16, hd=64, WINDOW=128.
// ---------------------------------------------------------------------------

#define NB 4
#define SQ 2048
#define NH 16
#define HD 64
#define DM 1024
#define WIN 128

typedef unsigned short u16;
typedef __bf16 bf16x8 __attribute__((ext_vector_type(8)));
typedef unsigned short us8 __attribute__((ext_vector_type(8)));
typedef unsigned short us4v __attribute__((ext_vector_type(4)));
typedef float f32x4 __attribute__((ext_vector_type(4)));

__device__ __forceinline__ u16 f2b(float f) {
  union { float f; unsigned u; } v; v.f = f;
  unsigned r = v.u + 0x7FFFu + ((v.u >> 16) & 1u);   // RNE
  return (u16)(r >> 16);
}

__device__ __forceinline__ bf16x8 as_bf(us8 v) {
  union { us8 a; bf16x8 b; } u; u.a = v; return u.b;
}

__device__ __forceinline__ f32x4 mfma16(bf16x8 a, bf16x8 b, f32x4 c) {
  return __builtin_amdgcn_mfma_f32_16x16x32_bf16(a, b, c, 0, 0, 0);
}

// async global->LDS, 16B per lane; LDS dest is wave-uniform base + lane*16
__device__ __forceinline__ void gl_lds16(const u16* g, u16* l) {
#if __has_builtin(__builtin_amdgcn_global_load_lds)
  __builtin_amdgcn_global_load_lds(
      (const __attribute__((address_space(1))) void*)g,
      (__attribute__((address_space(3))) void*)l, 16, 0, 0);
#else
  int lane = threadIdx.x & 63;
  *(us8*)(l + lane * 8) = *(const us8*)g;
#endif
}

// raw barrier with scheduler fences on both sides: no vmcnt(0)/lgkmcnt(0)
// drain; "memory" clobber keeps all memory ops on their side (rule 18).
#define MIDBAR()                                   \
  do {                                             \
    __builtin_amdgcn_sched_barrier(0);             \
    asm volatile("s_barrier" ::: "memory");        \
    __builtin_amdgcn_sched_barrier(0);             \
  } while (0)

// ---------------------------------------------------------------------------
// 1) prep: X fp32->bf16 (blocks 0..8191) ; W^T bf16 (blocks 8192..11263)
// ---------------------------------------------------------------------------
__global__ void k_prep(const float* __restrict__ X, u16* __restrict__ Xb,
                       const float* __restrict__ W0,
                       const float* __restrict__ W1,
                       const float* __restrict__ W2, u16* __restrict__ Wt) {
  int bx = blockIdx.x;
  int t = threadIdx.x;
  if (bx < 8192) {
    int idx = bx * 256 + t;
    float4 v = ((const float4*)X)[idx];
    us4v o = { f2b(v.x), f2b(v.y), f2b(v.z), f2b(v.w) };
    ((us4v*)Xb)[idx] = o;
    return;
  }
  int tb = bx - 8192;
  int mat = tb >> 10, rem = tb & 1023;
  const float* W = mat == 0 ? W0 : (mat == 1 ? W1 : W2);
  u16* dst = Wt + (size_t)mat * DM * DM;
  __shared__ float tile[32][33];
  int n0 = (rem & 31) * 32, k0 = (rem >> 5) * 32;
  int c = t & 31, r8 = t >> 5;
  for (int p = 0; p < 4; ++p) {
    int r = p * 8 + r8;
    tile[r][c] = W[(size_t)(k0 + r) * DM + n0 + c];
  }
  __syncthreads();
  for (int p = 0; p < 4; ++p) {
    int r = p * 8 + r8;
    dst[(size_t)(n0 + r) * DM + k0 + c] = f2b(tile[c][r]);
  }
}

// ---------------------------------------------------------------------------
// 2) GEMM: 128x128 tile, BK=64, 256 threads (4 waves, 2M x 2N, 64x64/wave).
//    Ring-2, ONE barrier per K-tile, vmcnt(0) before that barrier.
//    XOR-swizzled packed LDS (slot kg ^ (row&7)) -> conflict-free ds_read_b128.
//    Epilogues: mat 0/1 (Q,K) -> head-major [b][h][s][d];
//               mat 2  (V)   -> transposed [b][h][d][s] (8B vector stores).
// ---------------------------------------------------------------------------
__global__ __launch_bounds__(256, 2) void k_gemm(
    const u16* __restrict__ Xb, const u16* __restrict__ Wt,
    const float* __restrict__ bq, const float* __restrict__ bk,
    const float* __restrict__ bv,
    u16* __restrict__ Qh, u16* __restrict__ Kh, u16* __restrict__ VtG) {
  int mat = blockIdx.y >> 3;
  int n0 = (blockIdx.y & 7) * 128;
  int m0 = blockIdx.x * 128;
  const u16* Bw = Wt + (size_t)mat * DM * DM;
  const float* bias = mat == 0 ? bq : (mat == 1 ? bk : bv);

  // double buffer: (A 128x64 + B 128x64) bf16 x2 = 64 KiB -> 2 blocks/CU
  __shared__ u16 As[2][128 * 64];
  __shared__ u16 Bs[2][128 * 64];

  int tid = threadIdx.x;
  int lane = tid & 63, wave = tid >> 6;      // wave 0..3
  int wm = wave >> 1, wn = wave & 1;         // 2M x 2N, 64x64 per wave
  int col = lane & 15, g = lane >> 4;

  // staging: row = wave*32 + i*8 + (lane>>3), slot = (lane&7) ^ (row&7)
  int srow = lane >> 3;
  int skg = (lane & 7) ^ srow;
  const u16* gA = Xb + (size_t)(m0 + wave * 32 + srow) * DM + skg * 8;
  const u16* gB = Bw + (size_t)(n0 + wave * 32 + srow) * DM + skg * 8;

  f32x4 zero4 = {0.f, 0.f, 0.f, 0.f};
  f32x4 acc[4][4];
  for (int i = 0; i < 4; ++i)
    for (int j = 0; j < 4; ++j) acc[i][j] = zero4;

  // stage K-tile kt into buffer bi: 4 A-calls + 4 B-calls, 8 rows each
#define STAGE8(kt, bi)                                                  \
  do {                                                                  \
    _Pragma("unroll") for (int i = 0; i < 4; ++i)                       \
      gl_lds16(gA + (size_t)i * 8 * DM + (kt) * 64,                     \
               &As[bi][(wave * 32 + i * 8) * 64]);                      \
    _Pragma("unroll") for (int i = 0; i < 4; ++i)                       \
      gl_lds16(gB + (size_t)i * 8 * DM + (kt) * 64,                     \
               &Bs[bi][(wave * 32 + i * 8) * 64]);                      \
  } while (0)

  // prologue: tile 0 -> buf 0; publish before any read
  STAGE8(0, 0);
  asm volatile("s_waitcnt vmcnt(0)" ::: "memory");
  MIDBAR();

  for (int t = 0; t < 16; ++t) {
    int cur = t & 1, nxt = cur ^ 1;
    bf16x8 afl[2][4], bfl[2][4];
#pragma unroll
    for (int ks = 0; ks < 2; ++ks) {
      int kg = ((ks * 4 + g) ^ (col & 7)) * 8;
#pragma unroll
      for (int mi = 0; mi < 4; ++mi)
        afl[ks][mi] =
            *(const bf16x8*)&As[cur][(wm * 64 + mi * 16 + col) * 64 + kg];
#pragma unroll
      for (int ni = 0; ni < 4; ++ni)
        bfl[ks][ni] =
            *(const bf16x8*)&Bs[cur][(wn * 64 + ni * 16 + col) * 64 + kg];
    }
    if (t < 15) STAGE8(t + 1, nxt);   // overlaps the MFMA cluster below
    __builtin_amdgcn_s_setprio(1);
#pragma unroll
    for (int ks = 0; ks < 2; ++ks)
#pragma unroll
      for (int mi = 0; mi < 4; ++mi)
#pragma unroll
        for (int ni = 0; ni < 4; ++ni)
          acc[mi][ni] = mfma16(afl[ks][mi], bfl[ks][ni], acc[mi][ni]);
    __builtin_amdgcn_s_setprio(0);
    if (t < 15) asm volatile("s_waitcnt vmcnt(0)" ::: "memory");
    MIDBAR();  // publish: every wave's staged rows of tile t+1 landed
  }

#undef STAGE8

  float bvv[4];
  for (int ni = 0; ni < 4; ++ni)
    bvv[ni] = bias[n0 + wn * 64 + ni * 16 + col];

  if (mat < 2) {
    // head-major: addr = ((b*NH + h)*SQ + s)*HD + d
    u16* C = mat == 0 ? Qh : Kh;
    for (int mi = 0; mi < 4; ++mi) {
      int m = m0 + wm * 64 + mi * 16 + g * 4;
      int bb = m >> 11, s0 = m & 2047;
      for (int r = 0; r < 4; ++r) {
        size_t base = ((size_t)(bb * NH) * SQ + (s0 + r)) * HD;
        for (int ni = 0; ni < 4; ++ni) {
          int n = n0 + wn * 64 + ni * 16 + col;
          int h = n >> 6, d = n & 63;
          C[base + (size_t)h * SQ * HD + d] = f2b(acc[mi][ni][r] + bvv[ni]);
        }
      }
    }
  } else {
    // V^T: [b][h][d][s]; rows of C are consecutive tokens s -> 8B stores
    for (int mi = 0; mi < 4; ++mi) {
      int m = m0 + wm * 64 + mi * 16 + g * 4;
      int bb = m >> 11, s0 = m & 2047;
      for (int ni = 0; ni < 4; ++ni) {
        int n = n0 + wn * 64 + ni * 16 + col;
        us4v ov = { f2b(acc[mi][ni][0] + bvv[ni]), f2b(acc[mi][ni][1] + bvv[ni]),
                    f2b(acc[mi][ni][2] + bvv[ni]), f2b(acc[mi][ni][3] + bvv[ni]) };
        *(us4v*)&VtG[((size_t)(bb * 1024 + n)) * SQ + s0] = ov;
      }
    }
  }
}

// ---------------------------------------------------------------------------
// 3) Windowed flash attention. Block = 4 waves; each wave owns 32 queries of
//    one (b,h), loops over 5 key-chunks of 64. S^T = K*Q^T so each lane holds
//    4 consecutive keys -> vectorized P stores. No __syncthreads.
//    T1: XCD-aware bid swizzle -- all 16 q-tiles of a (b,h) on one XCD, so
//    the shared K/V windows stay L2-resident (per-XCD set: 8 heads x 512KB).
//    T14: V loads issued right after QK^T. T5: setprio around MFMA clusters.
// ---------------------------------------------------------------------------
__global__ __launch_bounds__(256) void k_attn(
    const u16* __restrict__ Qh, const u16* __restrict__ Kh,
    const u16* __restrict__ VtG, float* __restrict__ out) {
  int bid0 = blockIdx.x;
  // XCD swizzle: 1024 blocks, 8 XCDs -> XCD x gets contiguous wgid chunk
  // [x*128, (x+1)*128) = 8 full (b,h) groups. Bijective since 1024%8==0.
  int bid = ((bid0 & 7) << 7) | (bid0 >> 3);
  int b = bid >> 8;
  int h = (bid >> 4) & 15;
  int q0 = (bid & 15) << 7;
  int tid = threadIdx.x, lane = tid & 63, wave = tid >> 6;
  int col = lane & 15, g = lane >> 4;
  int qw = q0 + wave * 32;

  __shared__ u16 Ps[4][32 * 72];
  u16* Pw = Ps[wave];

  const u16* Qp = Qh + (size_t)(b * NH + h) * SQ * HD;
  const u16* Kp = Kh + (size_t)(b * NH + h) * SQ * HD;
  const u16* Vt = VtG + (size_t)(b * 1024 + h * 64) * SQ;

  // Q fragments (B operand: lane col = query, contiguous d)
  bf16x8 qf[2][2];
#pragma unroll
  for (int qb = 0; qb < 2; ++qb)
#pragma unroll
    for (int ks = 0; ks < 2; ++ks)
      qf[qb][ks] = *(const bf16x8*)&Qp[(size_t)(qw + qb * 16 + col) * HD +
                                       ks * 32 + g * 8];

  f32x4 zero4 = {0.f, 0.f, 0.f, 0.f};
  f32x4 o[2][4];
  float l8[2] = {0.f, 0.f};
#pragma unroll
  for (int qb = 0; qb < 2; ++qb)
#pragma unroll
    for (int nb = 0; nb < 4; ++nb) o[qb][nb] = zero4;

  const float SC = 0.18033688f;  // log2(e) / sqrt(64)
  int cbase = ((qw - 128) >> 6) << 6;

  for (int c = 0; c < 5; ++c) {
    int c0 = cbase + c * 64;
    if (c0 + 64 <= 0 || c0 >= SQ) continue;

    // S^T = K Q^T  (A = K: m = key, k = d;  B = Q: n = query)
    f32x4 s[4][2];
#pragma unroll
    for (int kb = 0; kb < 4; ++kb)
#pragma unroll
      for (int qb = 0; qb < 2; ++qb) s[kb][qb] = zero4;
#pragma unroll
    for (int ks = 0; ks < 2; ++ks) {
      bf16x8 kf[4];
#pragma unroll
      for (int kb = 0; kb < 4; ++kb) {
        int j = c0 + kb * 16 + col;
        us8 t = {0, 0, 0, 0, 0, 0, 0, 0};
        if ((unsigned)j < SQ)
          t = *(const us8*)&Kp[(size_t)j * HD + ks * 32 + g * 8];
        kf[kb] = as_bf(t);
      }
      __builtin_amdgcn_s_setprio(1);
#pragma unroll
      for (int kb = 0; kb < 4; ++kb)
#pragma unroll
        for (int qb = 0; qb < 2; ++qb)
          s[kb][qb] = mfma16(kf[kb], qf[qb][ks], s[kb][qb]);
      __builtin_amdgcn_s_setprio(0);
    }

    // T14: issue V loads now (consumed after softmax; kf regs reusable)
    us8 vraw[2][4];
#pragma unroll
    for (int ks = 0; ks < 2; ++ks) {
      int kv = c0 + ks * 32 + g * 8;
      bool okv = (unsigned)kv < SQ;
#pragma unroll
      for (int nb = 0; nb < 4; ++nb) {
        us8 t = {0, 0, 0, 0, 0, 0, 0, 0};
        if (okv) t = *(const us8*)&Vt[(size_t)(nb * 16 + col) * SQ + kv];
        vraw[ks][nb] = t;
      }
    }

    bool fullv = (c0 >= 0) && (c0 + 63 < SQ) && (c0 >= qw - 97) &&
                 (c0 + 63 <= qw + 128);
#pragma unroll
    for (int kb = 0; kb < 4; ++kb) {
#pragma unroll
      for (int qb = 0; qb < 2; ++qb) {
        float p[4];
#pragma unroll
        for (int r = 0; r < 4; ++r) {
          float e = __builtin_amdgcn_exp2f(s[kb][qb][r] * SC);
          if (!fullv) {
            int j = c0 + kb * 16 + g * 4 + r;
            int iq = qw + qb * 16 + col;
            bool ok = ((unsigned)j < SQ) && (iq - j <= WIN) && (j - iq <= WIN);
            e = ok ? e : 0.0f;
          }
          p[r] = e;
          l8[qb] += e;
        }
        union { __hip_bfloat162 h2[2]; us4v u4; } pk;
        pk.h2[0] = __float22bfloat162_rn(make_float2(p[0], p[1]));
        pk.h2[1] = __float22bfloat162_rn(make_float2(p[2], p[3]));
        *(us4v*)&Pw[(qb * 16 + col) * 72 + kb * 16 + g * 4] = pk.u4;
      }
    }

    // O += P V   (A = P: m = query, k = key; B = V^T: n = d, contiguous key)
#pragma unroll
    for (int ks = 0; ks < 2; ++ks) {
      bf16x8 pf[2];
#pragma unroll
      for (int qb = 0; qb < 2; ++qb)
        pf[qb] = *(const bf16x8*)&Pw[(qb * 16 + col) * 72 + ks * 32 + g * 8];
      __builtin_amdgcn_s_setprio(1);
#pragma unroll
      for (int qb = 0; qb < 2; ++qb)
#pragma unroll
        for (int nb = 0; nb < 4; ++nb)
          o[qb][nb] = mfma16(pf[qb], as_bf(vraw[ks][nb]), o[qb][nb]);
      __builtin_amdgcn_s_setprio(0);
    }
  }

  // denominators: lane(col,g) holds partial sum for q=col; reduce over g
#pragma unroll
  for (int qb = 0; qb < 2; ++qb) {
    l8[qb] += __shfl_xor(l8[qb], 16, 64);
    l8[qb] += __shfl_xor(l8[qb], 32, 64);
  }

#pragma unroll
  for (int qb = 0; qb < 2; ++qb)
#pragma unroll
    for (int r = 0; r < 4; ++r) {
      float inv = 1.0f / __shfl(l8[qb], g * 4 + r, 64);
      int iq = qw + qb * 16 + g * 4 + r;
      float* op = out + ((size_t)b * SQ + iq) * DM + h * HD;
#pragma unroll
      for (int nb = 0; nb < 4; ++nb) op[nb * 16 + col] = o[qb][nb][r] * inv;
    }
}

// ---------------------------------------------------------------------------
extern "C" void kernel_launch(void* const* d_in, const int* in_sizes, int n_in,
                              void* d_out, int out_size, void* d_ws,
                              size_t ws_size, hipStream_t stream) {
  const float* hs = (const float*)d_in[0];
  const float* Wq = (const float*)d_in[1];
  const float* bq = (const float*)d_in[2];
  const float* Wk = (const float*)d_in[3];
  const float* bk = (const float*)d_in[4];
  const float* Wv = (const float*)d_in[5];
  const float* bv = (const float*)d_in[6];
  float* out = (float*)d_out;
  char* ws = (char*)d_ws;

  // ws layout (bytes): Xb 16MB | Wt 6MB | Qh 16MB | Kh 16MB | Vt 16MB
  u16* Xb = (u16*)(ws);
  u16* Wt = (u16*)(ws + 16777216ULL);
  u16* Qh = (u16*)(ws + 23068672ULL);
  u16* Kh = (u16*)(ws + 39845888ULL);
  u16* Vt = (u16*)(ws + 56623104ULL);

  k_prep<<<dim3(11264), dim3(256), 0, stream>>>(hs, Xb, Wq, Wk, Wv, Wt);
  k_gemm<<<dim3(64, 24), dim3(256), 0, stream>>>(Xb, Wt, bq, bk, bv, Qh, Kh, Vt);
  k_attn<<<dim3(1024), dim3(256), 0, stream>>>(Qh, Kh, Vt, out);
}